// Round 14
// baseline (387.899 us; speedup 1.0000x reference)
//
#include <hip/hip_runtime.h>
#include <hip/hip_fp16.h>

typedef unsigned int uint;
typedef unsigned short ushort;

// Problem constants (from reference)
constexpr int DIM      = 64;
constexpr int N_USERS  = 100000;
constexpr int N_ITEMS  = 50000;
constexpr int N_CATS   = 1000;
constexpr int NE_UI    = 2000000;
constexpr int NE_UU    = 1000000;
constexpr int NE_IC    = 150000;
constexpr int N_LAYERS = 3;

// Unified row space: items [0,50K), users [50K,150K), cats [150K,151K)
constexpr int ROW_U0    = N_ITEMS;            // 50000
constexpr int ROW_C0    = N_ITEMS + N_USERS;  // 150000
constexpr int TOT_ROWS  = ROW_C0 + N_CATS;    // 151000
constexpr size_t TOT_EL = (size_t)TOT_ROWS * DIM;  // 9,664,000

constexpr int NE_USERS = NE_UI + NE_UU;  // 3,000,000 (ui + uu)
constexpr int NE_ITEMS = NE_UI + NE_IC;  // 2,150,000 (iu + ic)
constexpr int NE_CATS  = NE_IC;          //   150,000 (ci)

constexpr int SH_U = 9, SH_I = 8, SH_C = 2;             // bucket shifts
constexpr int NB_U = (N_USERS + 511) / 512;             // 196 buckets
constexpr int NB_I = (N_ITEMS + 255) / 256;             // 196
constexpr int NB_C = (N_CATS + 3) / 4;                  // 250
constexpr int CHUNK = 8192;
constexpr int CH_U = (NE_USERS + CHUNK - 1) / CHUNK;    // 367
constexpr int CH_I = (NE_ITEMS + CHUNK - 1) / CHUNK;    // 263
constexpr int CH_C = (NE_CATS  + CHUNK - 1) / CHUNK;    // 19

constexpr int COLSHIFT = 18;         // pack: (local_row << 18) | global_col
constexpr int COLMASK  = 0x3FFFF;    // global_col < 151000 < 2^18; lr < 512

constexpr int CAST_BLKS = 1024;      // blocks of fused_cast_hist doing the cast

// ---------------- fp16 helpers ----------------

__device__ __forceinline__ ushort f2h(float f) { return __half_as_ushort(__float2half_rn(f)); }

// ---------------- fused CSR build (3 relations in one pass each) ----------------

struct RelSrc {
    const int* rowsA; const int* colsA; const float* valsA; int neA; int offA;
    const int* rowsB; const int* colsB; const float* valsB; int neB; int offB;
    int shift; int n_out;
};

struct BuildParams {
    RelSrc rel[3];          // 0=users, 1=items, 2=cats
    int* bcnt;              // 3*256
    int* boffs;             // 3*257
    int* cursor;            // 3*256
    int2* bucketed[3];
    int* ptr[3];
    int2* edges[3];
};

// blocks [0,CAST_BLKS): cast embeddings -> unified fp16 table
// blocks [CAST_BLKS, CAST_BLKS+3*256): 256-bin bucket histogram per relation
__global__ __launch_bounds__(256) void fused_cast_hist(BuildParams P,
                                                       const float* __restrict__ ue,
                                                       const float* __restrict__ ie,
                                                       const float* __restrict__ ce,
                                                       ushort* __restrict__ H) {
    int bid = blockIdx.x;
    if (bid < CAST_BLKS) {
        constexpr int NI8 = (N_ITEMS * DIM) / 8;
        constexpr int NU8 = (N_USERS * DIM) / 8;
        constexpr int NC8 = (N_CATS  * DIM) / 8;
        constexpr int TOT8 = NI8 + NU8 + NC8;
        int st = CAST_BLKS * 256;
        for (int i = bid * 256 + threadIdx.x; i < TOT8; i += st) {
            const float* src; int s8;
            if (i < NI8)            { src = ie; s8 = i; }
            else if (i < NI8 + NU8) { src = ue; s8 = i - NI8; }
            else                    { src = ce; s8 = i - NI8 - NU8; }
            float4 a = reinterpret_cast<const float4*>(src)[2 * s8];
            float4 b = reinterpret_cast<const float4*>(src)[2 * s8 + 1];
            uint4 v;
            v.x = (uint)f2h(a.x) | ((uint)f2h(a.y) << 16);
            v.y = (uint)f2h(a.z) | ((uint)f2h(a.w) << 16);
            v.z = (uint)f2h(b.x) | ((uint)f2h(b.y) << 16);
            v.w = (uint)f2h(b.z) | ((uint)f2h(b.w) << 16);
            reinterpret_cast<uint4*>(H)[i] = v;
        }
    } else {
        int b2 = bid - CAST_BLKS;
        int rel = b2 >> 8;
        int lbk = b2 & 255;
        RelSrc R = P.rel[rel];
        __shared__ int lb[256];
        lb[threadIdx.x] = 0;
        __syncthreads();
        int ne = R.neA + R.neB;
        for (int i = lbk * 256 + threadIdx.x; i < ne; i += 256 * 256) {
            int r = (i < R.neA) ? R.rowsA[i] : R.rowsB[i - R.neA];
            atomicAdd(&lb[r >> R.shift], 1);
        }
        __syncthreads();
        if (lb[threadIdx.x]) atomicAdd(&P.bcnt[rel * 256 + threadIdx.x], lb[threadIdx.x]);
    }
}

__global__ void fused_scan(const int* __restrict__ bcnt, int* __restrict__ boffs,
                           int* __restrict__ cursor) {
    __shared__ int lds[256];
    int rel = blockIdx.x, tid = threadIdx.x;
    int v = bcnt[rel * 256 + tid];
    lds[tid] = v;
    __syncthreads();
    for (int off = 1; off < 256; off <<= 1) {
        int t = (tid >= off) ? lds[tid - off] : 0;
        __syncthreads();
        lds[tid] += t;
        __syncthreads();
    }
    int excl = lds[tid] - v;
    boffs[rel * 257 + tid] = excl;
    cursor[rel * 256 + tid] = excl;
    if (tid == 255) boffs[rel * 257 + 256] = lds[255];
}

// Level 1: LDS-staged multisplit into <=256 coarse buckets per relation.
// 1024 threads x 76KB LDS: 2 blocks/CU x 16 waves = 32 waves/CU (round-10 lesson).
__global__ __launch_bounds__(1024) void fused_scatter(BuildParams P, int c0, int c01) {
    __shared__ int2 stage[CHUNK];
    __shared__ unsigned char sb[CHUNK];
    __shared__ int hist[256], lbase[256], gbase[256], cnt[256];
    int bid = blockIdx.x, tid = threadIdx.x;
    int rel = (bid < c0) ? 0 : ((bid < c01) ? 1 : 2);
    int ch  = bid - ((rel == 0) ? 0 : ((rel == 1) ? c0 : c01));
    RelSrc R = P.rel[rel];
    int ne = R.neA + R.neB;
    int base = ch * CHUNK;
    int nedge = min(CHUNK, ne - base);
    int* cursor = P.cursor + rel * 256;
    int2* out = P.bucketed[rel];

    if (tid < 256) hist[tid] = 0;
    __syncthreads();
    for (int k = tid; k < nedge; k += 1024) {
        int gi = base + k;
        int r = (gi < R.neA) ? R.rowsA[gi] : R.rowsB[gi - R.neA];
        atomicAdd(&hist[r >> R.shift], 1);
    }
    __syncthreads();
    if (tid < 256) lbase[tid] = hist[tid];
    __syncthreads();
    for (int off = 1; off < 256; off <<= 1) {
        int t = (tid < 256 && tid >= off) ? lbase[tid - off] : 0;
        __syncthreads();
        if (tid < 256) lbase[tid] += t;
        __syncthreads();
    }
    if (tid < 256) {
        int excl = lbase[tid] - hist[tid];
        cnt[tid] = excl;
        gbase[tid] = hist[tid] ? atomicAdd(&cursor[tid], hist[tid]) : 0;
        lbase[tid] = excl;  // own-slot rewrite, safe
    }
    __syncthreads();
    for (int k = tid; k < nedge; k += 1024) {
        int gi = base + k;
        int r, c; float v;
        if (gi < R.neA) { r = R.rowsA[gi]; c = R.colsA[gi] + R.offA; v = R.valsA[gi]; }
        else { int q = gi - R.neA; r = R.rowsB[q]; c = R.colsB[q] + R.offB; v = R.valsB[q]; }
        int b = r >> R.shift;
        int slot = atomicAdd(&cnt[b], 1);
        int lr = r - (b << R.shift);
        stage[slot] = make_int2((lr << COLSHIFT) | c, __float_as_int(v));
        sb[slot] = (unsigned char)b;
    }
    __syncthreads();
    for (int j = tid; j < nedge; j += 1024) {
        int b = sb[j];
        out[gbase[b] + (j - lbase[b])] = stage[j];
    }
}

// Level 2: one block per bucket; hist + scan + ptr write + scatter, all L2-local.
// Final edges store .x = col * 128 (byte offset into fp16 H row) and
// .y = half2(w, w) pre-packed for v_pk_fma_f16 in the layer loop.
__global__ __launch_bounds__(256) void fused_finalize(BuildParams P, int nb0, int nb01,
                                                      int nbu, int nbi, int nbc) {
    __shared__ int h[512], psum[256], cur[512];
    int bg = blockIdx.x, tid = threadIdx.x;
    int rel = (bg < nb0) ? 0 : ((bg < nb01) ? 1 : 2);
    int lb  = bg - ((rel == 0) ? 0 : ((rel == 1) ? nb0 : nb01));
    int nb  = (rel == 0) ? nbu : ((rel == 1) ? nbi : nbc);
    RelSrc R = P.rel[rel];
    const int* boffs = P.boffs + rel * 257;
    const int2* bucketed = P.bucketed[rel];
    int* ptr = P.ptr[rel];
    int2* edges = P.edges[rel];

    int s = boffs[lb], e = boffs[lb + 1];
    int base_row = lb << R.shift;
    int nrows_b = min(1 << R.shift, R.n_out - base_row);
    h[tid] = 0; h[tid + 256] = 0;
    __syncthreads();
    for (int j = s + tid; j < e; j += 256)
        atomicAdd(&h[(unsigned)bucketed[j].x >> COLSHIFT], 1);
    __syncthreads();
    int a0 = h[2 * tid], a1 = h[2 * tid + 1];
    psum[tid] = a0 + a1;
    __syncthreads();
    for (int off = 1; off < 256; off <<= 1) {
        int t = (tid >= off) ? psum[tid - off] : 0;
        __syncthreads();
        psum[tid] += t;
        __syncthreads();
    }
    int pex = (tid == 0) ? 0 : psum[tid - 1];
    cur[2 * tid] = pex;
    cur[2 * tid + 1] = pex + a0;
    if (2 * tid < nrows_b)     ptr[base_row + 2 * tid]     = s + pex;
    if (2 * tid + 1 < nrows_b) ptr[base_row + 2 * tid + 1] = s + pex + a0;
    if (lb == nb - 1 && tid == 0) ptr[R.n_out] = boffs[nb];
    __syncthreads();
    for (int j = s + tid; j < e; j += 256) {
        int2 w = bucketed[j];
        int lr = (unsigned)w.x >> COLSHIFT;
        int slot = atomicAdd(&cur[lr], 1);
        __half2 wh = __float2half2_rn(__int_as_float(w.y));
        edges[s + slot] = make_int2((w.x & COLMASK) << 7,
                                    (int)*reinterpret_cast<uint*>(&wh));
    }
}

// ---------------- fused layer kernel (all 3 node types, fp16 H) ----------------
// Wave: 8 edge-groups (grp=lane>>3) x 8 lanes (sub=lane&7) x 16B (8 fp16).
// Packed fp16 math: 4 v_pk_fma_f16 per edge-lane (was 8 f32 FMA + 8 unpacks);
// accumulator is 4x half2. x4 clamped batch, all gathers in flight.

__device__ __forceinline__ void hfma4(uint4 hv, uint w, uint* acc) {
    __half2 wh = *reinterpret_cast<__half2*>(&w);
    __half2* a = reinterpret_cast<__half2*>(acc);
    a[0] = __hfma2(*reinterpret_cast<__half2*>(&hv.x), wh, a[0]);
    a[1] = __hfma2(*reinterpret_cast<__half2*>(&hv.y), wh, a[1]);
    a[2] = __hfma2(*reinterpret_cast<__half2*>(&hv.z), wh, a[2]);
    a[3] = __hfma2(*reinterpret_cast<__half2*>(&hv.w), wh, a[3]);
}

__device__ __forceinline__ void gather8(const int* __restrict__ ptr,
                                        const int2* __restrict__ edges,
                                        const ushort* __restrict__ H,
                                        int r, int grp, int sub, uint* acc) {
    int s = ptr[r], e = ptr[r + 1];
    int L = (e - s + 7) >> 3;          // edges per group (contiguous range)
    int gs = s + grp * L;
    int ge = min(gs + L, e);
    const char* Hb = (const char*)H + sub * 16;   // edges[].x is a byte offset
    for (int j0 = gs; j0 < ge; j0 += 4) {
        int j1 = j0 + 1, j2 = j0 + 2, j3 = j0 + 3;
        int2 e0 = edges[j0];
        int2 e1 = edges[j1 < ge ? j1 : j0];
        int2 e2 = edges[j2 < ge ? j2 : j0];
        int2 e3 = edges[j3 < ge ? j3 : j0];
        uint4 h0 = *reinterpret_cast<const uint4*>(Hb + e0.x);
        uint4 h1 = *reinterpret_cast<const uint4*>(Hb + e1.x);
        uint4 h2 = *reinterpret_cast<const uint4*>(Hb + e2.x);
        uint4 h3 = *reinterpret_cast<const uint4*>(Hb + e3.x);
        uint w1 = (j1 < ge) ? (uint)e1.y : 0u;
        uint w2 = (j2 < ge) ? (uint)e2.y : 0u;
        uint w3 = (j3 < ge) ? (uint)e3.y : 0u;
        hfma4(h0, (uint)e0.y, acc);
        hfma4(h1, w1, acc);
        hfma4(h2, w2, acc);
        hfma4(h3, w3, acc);
    }
}

__device__ __forceinline__ void xreduceh(uint* a) {
#pragma unroll
    for (int m = 8; m <= 32; m <<= 1)
#pragma unroll
        for (int k = 0; k < 4; ++k) {
            uint o = __shfl_xor(a[k], m);
            __half2 s = __hadd2(*reinterpret_cast<__half2*>(&a[k]),
                                *reinterpret_cast<__half2*>(&o));
            a[k] = *reinterpret_cast<uint*>(&s);
        }
}

__global__ void fused_layer(const int* __restrict__ u_ptr, const int2* __restrict__ u_e,
                            const int* __restrict__ i_ptr, const int2* __restrict__ i_e,
                            const int* __restrict__ c_ptr, const int2* __restrict__ c_e,
                            const ushort* __restrict__ Hcur, ushort* __restrict__ Hnxt,
                            const ushort* __restrict__ H1, const ushort* __restrict__ H2,
                            float* __restrict__ sum_u, float* __restrict__ sum_i,
                            float* __restrict__ out_c,
                            const float* __restrict__ user_emb, const float* __restrict__ item_emb,
                            float scale, int last) {
    int wid  = (blockIdx.x * blockDim.x + threadIdx.x) >> 6;  // global row
    int lane = threadIdx.x & 63;
    if (wid >= TOT_ROWS) return;
    int grp = lane >> 3, sub = lane & 7;
    uint acc[4] = {0u, 0u, 0u, 0u};
    const int* ptr; const int2* eg; int lr;
    if (wid < ROW_U0)      { ptr = i_ptr; eg = i_e; lr = wid; }            // items
    else if (wid < ROW_C0) { ptr = u_ptr; eg = u_e; lr = wid - ROW_U0; }   // users
    else                   { ptr = c_ptr; eg = c_e; lr = wid - ROW_C0; }   // cats
    gather8(ptr, eg, Hcur, lr, grp, sub, acc);
    xreduceh(acc);  // all lanes hold final fp16 acc for their 8 dims
    if (grp != 0) return;
    size_t o = (size_t)wid * DIM + sub * 8;
    if (!last) {
        *reinterpret_cast<uint4*>(Hnxt + o) = make_uint4(acc[0], acc[1], acc[2], acc[3]);
        return;
    }
    float f[8];
#pragma unroll
    for (int k = 0; k < 4; ++k) {
        __half2 v = *reinterpret_cast<__half2*>(&acc[k]);
        f[2 * k]     = __low2float(v);
        f[2 * k + 1] = __high2float(v);
    }
    if (wid < ROW_C0) {
        const float* emb; float* dst; size_t so;
        if (wid < ROW_U0) { emb = item_emb; dst = sum_i; so = o; }
        else { emb = user_emb; dst = sum_u; so = (size_t)lr * DIM + sub * 8; }
        uint4 a1 = *reinterpret_cast<const uint4*>(H1 + o);
        uint4 a2 = *reinterpret_cast<const uint4*>(H2 + o);
        float g1[8], g2[8];
        uint* p1 = &a1.x; uint* p2 = &a2.x;
#pragma unroll
        for (int k = 0; k < 4; ++k) {
            __half2 v1 = *reinterpret_cast<__half2*>(&p1[k]);
            __half2 v2 = *reinterpret_cast<__half2*>(&p2[k]);
            g1[2 * k] = __low2float(v1); g1[2 * k + 1] = __high2float(v1);
            g2[2 * k] = __low2float(v2); g2[2 * k + 1] = __high2float(v2);
        }
        const float4* ep = reinterpret_cast<const float4*>(emb + so);
        float4 b0 = ep[0], b1 = ep[1];
        float4 r0, r1;
        r0.x = (b0.x + g1[0] + g2[0] + f[0]) * scale;
        r0.y = (b0.y + g1[1] + g2[1] + f[1]) * scale;
        r0.z = (b0.z + g1[2] + g2[2] + f[2]) * scale;
        r0.w = (b0.w + g1[3] + g2[3] + f[3]) * scale;
        r1.x = (b1.x + g1[4] + g2[4] + f[4]) * scale;
        r1.y = (b1.y + g1[5] + g2[5] + f[5]) * scale;
        r1.z = (b1.z + g1[6] + g2[6] + f[6]) * scale;
        r1.w = (b1.w + g1[7] + g2[7] + f[7]) * scale;
        float4* dp = reinterpret_cast<float4*>(dst + so);
        dp[0] = r0; dp[1] = r1;
    } else {
        float4* op = reinterpret_cast<float4*>(out_c + (size_t)lr * DIM + sub * 8);
        op[0] = make_float4(f[0], f[1], f[2], f[3]);
        op[1] = make_float4(f[4], f[5], f[6], f[7]);
    }
}

// ---------------- fallback (push-atomic fp32 path) ----------------

__global__ void spmm_edges(const int* __restrict__ rows, const int* __restrict__ cols,
                           const float* __restrict__ vals, const float* __restrict__ H,
                           float* __restrict__ out, int ne) {
    int tid  = blockIdx.x * blockDim.x + threadIdx.x;
    int e    = tid >> 6;
    int lane = threadIdx.x & 63;
    if (e >= ne) return;
    float x = vals[e] * H[(size_t)cols[e] * DIM + lane];
    unsafeAtomicAdd(&out[(size_t)rows[e] * DIM + lane], x);
}

__global__ void accum_kernel(float* __restrict__ sum, const float* __restrict__ h, int n) {
    int i = blockIdx.x * blockDim.x + threadIdx.x;
    int st = gridDim.x * blockDim.x;
    for (; i < n; i += st) sum[i] += h[i];
}

__global__ void scale_kernel(float* __restrict__ p, int n, float s) {
    int i = blockIdx.x * blockDim.x + threadIdx.x;
    int st = gridDim.x * blockDim.x;
    for (; i < n; i += st) p[i] *= s;
}

// ---------------- host ----------------

extern "C" void kernel_launch(void* const* d_in, const int* in_sizes, int n_in,
                              void* d_out, int out_size, void* d_ws, size_t ws_size,
                              hipStream_t stream) {
    const float* user_emb = (const float*)d_in[0];
    const float* item_emb = (const float*)d_in[1];
    const float* cat_emb  = (const float*)d_in[2];
    const float* ui_vals  = (const float*)d_in[3];
    const float* iu_vals  = (const float*)d_in[4];
    const float* uu_vals  = (const float*)d_in[5];
    const float* ic_vals  = (const float*)d_in[6];
    const float* ci_vals  = (const float*)d_in[7];
    const int*   ui_rows  = (const int*)d_in[8];
    const int*   ui_cols  = (const int*)d_in[9];
    const int*   iu_rows  = (const int*)d_in[10];
    const int*   iu_cols  = (const int*)d_in[11];
    const int*   uu_rows  = (const int*)d_in[12];
    const int*   uu_cols  = (const int*)d_in[13];
    const int*   ic_rows  = (const int*)d_in[14];
    const int*   ic_cols  = (const int*)d_in[15];
    const int*   ci_rows  = (const int*)d_in[16];
    const int*   ci_cols  = (const int*)d_in[17];

    constexpr size_t NU = (size_t)N_USERS * DIM;
    constexpr size_t NI = (size_t)N_ITEMS * DIM;
    constexpr size_t NC = (size_t)N_CATS  * DIM;

    float* sum_u = (float*)d_out;
    float* sum_i = sum_u + NU;
    float* out_c = sum_i + NI;

    const int blk = 256;
    const float inv = 1.0f / (N_LAYERS + 1);

    // ---- workspace bump allocator (bytes, 16B-aligned) ----
    unsigned char* wb = (unsigned char*)d_ws;
    size_t woff = 0;
    auto take = [&](size_t bytes) -> void* {
        void* p = wb + woff;
        woff = (woff + bytes + 15) & ~(size_t)15;
        return p;
    };
    ushort* Hbuf[3] = { (ushort*)take(TOT_EL * 2), (ushort*)take(TOT_EL * 2),
                        (ushort*)take(TOT_EL * 2) };
    int* u_ptr = (int*)take(((size_t)N_USERS + 1) * 4);
    int* i_ptr = (int*)take(((size_t)N_ITEMS + 1) * 4);
    int* c_ptr = (int*)take(((size_t)N_CATS  + 1) * 4);
    int2* u_e = (int2*)take((size_t)NE_USERS * 8);
    int2* i_e = (int2*)take((size_t)NE_ITEMS * 8);
    int2* c_e = (int2*)take((size_t)NE_CATS  * 8);
    int* bcnt   = (int*)take(3 * 256 * 4);
    int* boffs  = (int*)take(3 * 257 * 4);
    int* cursor = (int*)take(3 * 256 * 4);
    size_t needed_bytes = woff;  // ~101 MB
    // bucketed scratch overlays: items -> Hbuf[1] (17.2 < 19.3 MB, dead until
    // layer 0 writes it), cats -> Hbuf[2], users -> d_out (24 < 38.6 MB, every
    // element overwritten by the last layer).
    int2* bk_u = (int2*)d_out;
    int2* bk_i = (int2*)Hbuf[1];
    int2* bk_c = (int2*)Hbuf[2];

    if (ws_size >= needed_bytes) {
        BuildParams P;
        P.rel[0] = { ui_rows, ui_cols, ui_vals, NE_UI, 0,
                     uu_rows, uu_cols, uu_vals, NE_UU, ROW_U0, SH_U, N_USERS };
        P.rel[1] = { iu_rows, iu_cols, iu_vals, NE_UI, ROW_U0,
                     ic_rows, ic_cols, ic_vals, NE_IC, ROW_C0, SH_I, N_ITEMS };
        P.rel[2] = { ci_rows, ci_cols, ci_vals, NE_IC, 0,
                     nullptr, nullptr, nullptr, 0, 0, SH_C, N_CATS };
        P.bcnt = bcnt; P.boffs = boffs; P.cursor = cursor;
        P.bucketed[0] = bk_u; P.bucketed[1] = bk_i; P.bucketed[2] = bk_c;
        P.ptr[0] = u_ptr; P.ptr[1] = i_ptr; P.ptr[2] = c_ptr;
        P.edges[0] = u_e; P.edges[1] = i_e; P.edges[2] = c_e;

        hipMemsetAsync(bcnt, 0, 3 * 256 * sizeof(int), stream);
        fused_cast_hist<<<CAST_BLKS + 3 * 256, blk, 0, stream>>>(P, user_emb, item_emb,
                                                                 cat_emb, Hbuf[0]);
        fused_scan<<<3, blk, 0, stream>>>(bcnt, boffs, cursor);
        fused_scatter<<<CH_U + CH_I + CH_C, 1024, 0, stream>>>(P, CH_U, CH_U + CH_I);
        fused_finalize<<<NB_U + NB_I + NB_C, blk, 0, stream>>>(P, NB_U, NB_U + NB_I,
                                                               NB_U, NB_I, NB_C);

        int grid = (TOT_ROWS * 64 + blk - 1) / blk;  // 4 rows (waves) per block
        for (int l = 0; l < N_LAYERS; ++l) {
            fused_layer<<<grid, blk, 0, stream>>>(u_ptr, u_e, i_ptr, i_e, c_ptr, c_e,
                                                  Hbuf[l], Hbuf[l + 1 < 3 ? l + 1 : 0],
                                                  Hbuf[1], Hbuf[2],
                                                  sum_u, sum_i, out_c,
                                                  user_emb, item_emb,
                                                  inv, l == N_LAYERS - 1);
        }
    } else {
        // ---- fallback: push-atomic fp32 path (own layout at front of ws) ----
        float* ws = (float*)d_ws;
        float* f_u[2] = { ws,               ws + NU };
        float* f_i[2] = { ws + 2 * NU,      ws + 2 * NU + NI };
        float* f_c[2] = { ws + 2 * NU + 2 * NI, ws + 2 * NU + 2 * NI + NC };
        hipMemcpyAsync(f_u[0], user_emb, NU * sizeof(float), hipMemcpyDeviceToDevice, stream);
        hipMemcpyAsync(f_i[0], item_emb, NI * sizeof(float), hipMemcpyDeviceToDevice, stream);
        hipMemcpyAsync(f_c[0], cat_emb,  NC * sizeof(float), hipMemcpyDeviceToDevice, stream);
        hipMemcpyAsync(sum_u,  user_emb, NU * sizeof(float), hipMemcpyDeviceToDevice, stream);
        hipMemcpyAsync(sum_i,  item_emb, NI * sizeof(float), hipMemcpyDeviceToDevice, stream);
        const int ew_grid = 2048;
        int cur = 0;
        for (int l = 0; l < N_LAYERS; ++l) {
            int nxt = cur ^ 1;
            hipMemsetAsync(f_u[nxt], 0, NU * sizeof(float), stream);
            hipMemsetAsync(f_i[nxt], 0, NI * sizeof(float), stream);
            hipMemsetAsync(f_c[nxt], 0, NC * sizeof(float), stream);
            spmm_edges<<<(NE_UI + 3) / 4, blk, 0, stream>>>(ui_rows, ui_cols, ui_vals, f_i[cur], f_u[nxt], NE_UI);
            spmm_edges<<<(NE_UU + 3) / 4, blk, 0, stream>>>(uu_rows, uu_cols, uu_vals, f_u[cur], f_u[nxt], NE_UU);
            spmm_edges<<<(NE_UI + 3) / 4, blk, 0, stream>>>(iu_rows, iu_cols, iu_vals, f_u[cur], f_i[nxt], NE_UI);
            spmm_edges<<<(NE_IC + 3) / 4, blk, 0, stream>>>(ic_rows, ic_cols, ic_vals, f_c[cur], f_i[nxt], NE_IC);
            spmm_edges<<<(NE_IC + 3) / 4, blk, 0, stream>>>(ci_rows, ci_cols, ci_vals, f_i[cur], f_c[nxt], NE_IC);
            accum_kernel<<<ew_grid, blk, 0, stream>>>(sum_u, f_u[nxt], (int)NU);
            accum_kernel<<<ew_grid, blk, 0, stream>>>(sum_i, f_i[nxt], (int)NI);
            cur = nxt;
        }
        scale_kernel<<<ew_grid, blk, 0, stream>>>(sum_u, (int)NU, inv);
        scale_kernel<<<ew_grid, blk, 0, stream>>>(sum_i, (int)NI, inv);
        hipMemcpyAsync(out_c, f_c[cur], NC * sizeof(float), hipMemcpyDeviceToDevice, stream);
    }
}